// Round 1
// baseline (604.424 us; speedup 1.0000x reference)
//
#include <hip/hip_runtime.h>

// Problem constants
constexpr int cB   = 2;
constexpr int cS   = 2048;
constexpr int cH   = 2048;
constexpr int cNH  = 16;
constexpr int cKVH = 4;
constexpr int cHD  = 128;
constexpr int cQD  = 2048;   // NH*HD
constexpr int cKVD = 512;    // KVH*HD
constexpr int cNQKV = 3072;  // QD + 2*KVD
constexpr int cNTOK = 4096;  // B*S
#define ATTN_SCALE 0.08838834764831845f

typedef __bf16 bf16;
typedef __attribute__((ext_vector_type(8))) __bf16 bf16x8;
typedef __attribute__((ext_vector_type(4))) __bf16 bf16x4;
typedef __attribute__((ext_vector_type(4))) float  f32x4;

__device__ __forceinline__ void async_load16(const bf16* g, bf16* l) {
    __builtin_amdgcn_global_load_lds(
        (const __attribute__((address_space(1))) void*)g,
        (__attribute__((address_space(3))) void*)l, 16, 0, 0);
}

// ---------------- fp32 -> bf16 convert (vectorized) ----------------
__global__ void conv_f32_bf16(const float* __restrict__ in, bf16* __restrict__ out) {
    int i = (blockIdx.x * 256 + threadIdx.x) * 4;
    f32x4 v = *(const f32x4*)(in + i);
    bf16x4 o;
    o[0] = (bf16)v[0]; o[1] = (bf16)v[1]; o[2] = (bf16)v[2]; o[3] = (bf16)v[3];
    *(bf16x4*)(out + i) = o;
}

// ---------------- fold LoRA into combined QKV weight (N=3072, K=2048), store (N,K) bf16 ----------------
__global__ void prep_w(const float* __restrict__ qw, const float* __restrict__ kw, const float* __restrict__ vw,
                       const float* __restrict__ qA, const float* __restrict__ qB,
                       const float* __restrict__ kA, const float* __restrict__ kB,
                       const float* __restrict__ vA, const float* __restrict__ vB,
                       bf16* __restrict__ Wc) {
    const int idx = blockIdx.x * 256 + threadIdx.x;   // < 3072*2048
    const int n = idx >> 11, k = idx & 2047;
    const float* W; const float* Am; const float* Bm; int nn, nd;
    if (n < cQD)             { W = qw; Am = qA; Bm = qB; nn = n;          nd = cQD; }
    else if (n < cQD + cKVD) { W = kw; Am = kA; Bm = kB; nn = n - cQD;    nd = cKVD; }
    else                     { W = vw; Am = vA; Bm = vB; nn = n - cQD - cKVD; nd = cKVD; }
    float acc = 0.f;
    #pragma unroll
    for (int r = 0; r < 16; ++r) acc += Am[k * 16 + r] * Bm[r * nd + nn];
    Wc[(size_t)n * cH + k] = (bf16)(W[(size_t)nn * cH + k] + 2.0f * acc);
}

__global__ void prep_bias(const float* __restrict__ qb, const float* __restrict__ kb,
                          const float* __restrict__ vb, float* __restrict__ biasc) {
    int n = blockIdx.x * 256 + threadIdx.x;
    if (n >= cNQKV) return;
    biasc[n] = (n < cQD) ? qb[n] : (n < cQD + cKVD ? kb[n - cQD] : vb[n - cQD - cKVD]);
}

// ---------------- 128x128-tile bf16 GEMM, B given as (N,K) ("B^T"), m97 structure ----------------
// OUTF32=0: bf16 out + bias; OUTF32=1: fp32 out, no bias
template <int OUTF32>
__global__ __launch_bounds__(256) void gemm_bt(const bf16* __restrict__ A, const bf16* __restrict__ Bw,
                                               const float* __restrict__ bias, void* __restrict__ Cp,
                                               int M, int N, int K) {
    __shared__ bf16 Al[128 * 32];
    __shared__ bf16 Bl[128 * 32];
    const int tid = threadIdx.x;
    const int wave = tid >> 6, lane = tid & 63;
    const int quad = lane >> 4, l16 = lane & 15;
    const int wr = wave >> 1, wc = wave & 1;
    const long bm = (long)blockIdx.y * 128, bn = (long)blockIdx.x * 128;

    f32x4 acc[4][4];
    #pragma unroll
    for (int i = 0; i < 4; ++i)
        #pragma unroll
        for (int c = 0; c < 4; ++c) acc[i][c] = f32x4{0.f, 0.f, 0.f, 0.f};

    const int r0 = lane >> 2;         // 0..15
    const int kc = (lane & 3) * 8;    // 0,8,16,24

    for (int k0 = 0; k0 < K; k0 += 32) {
        __syncthreads();
        #pragma unroll
        for (int j = 0; j < 2; ++j) {
            const int rb = (wave * 2 + j) * 16;
            const int row = rb + r0;
            async_load16(A  + (size_t)(bm + row) * K + k0 + kc, &Al[rb * 32 + r0 * 32 + kc]);
            async_load16(Bw + (size_t)(bn + row) * K + k0 + kc, &Bl[rb * 32 + r0 * 32 + kc]);
        }
        __syncthreads();
        bf16x8 af[4], bfr[4];
        #pragma unroll
        for (int i = 0; i < 4; ++i) af[i]  = *(const bf16x8*)&Al[(wr * 64 + i * 16 + l16) * 32 + quad * 8];
        #pragma unroll
        for (int c = 0; c < 4; ++c) bfr[c] = *(const bf16x8*)&Bl[(wc * 64 + c * 16 + l16) * 32 + quad * 8];
        #pragma unroll
        for (int i = 0; i < 4; ++i)
            #pragma unroll
            for (int c = 0; c < 4; ++c)
                acc[i][c] = __builtin_amdgcn_mfma_f32_16x16x32_bf16(af[i], bfr[c], acc[i][c], 0, 0, 0);
    }

    #pragma unroll
    for (int i = 0; i < 4; ++i)
        #pragma unroll
        for (int c = 0; c < 4; ++c) {
            const long m0 = bm + wr * 64 + i * 16 + quad * 4;
            const long n  = bn + wc * 64 + c * 16 + l16;
            #pragma unroll
            for (int r = 0; r < 4; ++r) {
                float v = acc[i][c][r];
                if (OUTF32) {
                    ((float*)Cp)[(m0 + r) * N + n] = v;
                } else {
                    v += bias[n];
                    ((bf16*)Cp)[(m0 + r) * N + n] = (bf16)v;
                }
            }
        }
}

// ---------------- RoPE + reorder to head-major Q/K/V ----------------
__global__ void rope_reorder(const bf16* __restrict__ Y, const float* __restrict__ cosb,
                             const float* __restrict__ sinb,
                             bf16* __restrict__ Qr, bf16* __restrict__ Kr, bf16* __restrict__ Vr) {
    const int idx = blockIdx.x * 256 + threadIdx.x;  // < 4096*3072
    const int t = idx / cNQKV;
    const int col = idx - t * cNQKV;
    const int b = t >> 11, s = t & 2047;
    const size_t yrow = (size_t)t * cNQKV;
    if (col < cQD) {
        const int h = col >> 7, d = col & 127;
        float y  = (float)Y[yrow + col];
        float pr = (d < 64) ? -(float)Y[yrow + col + 64] : (float)Y[yrow + col - 64];
        float cv = cosb[(size_t)t * cHD + d];
        float sv = sinb[(size_t)t * cHD + d];
        Qr[((size_t)(b * cNH + h) * cS + s) * cHD + d] = (bf16)(y * cv + pr * sv);
    } else if (col < cQD + cKVD) {
        const int c2 = col - cQD;
        const int h = c2 >> 7, d = c2 & 127;
        float y  = (float)Y[yrow + col];
        float pr = (d < 64) ? -(float)Y[yrow + col + 64] : (float)Y[yrow + col - 64];
        float cv = cosb[(size_t)t * cHD + d];
        float sv = sinb[(size_t)t * cHD + d];
        Kr[((size_t)(b * cKVH + h) * cS + s) * cHD + d] = (bf16)(y * cv + pr * sv);
    } else {
        const int c2 = col - cQD - cKVD;
        const int h = c2 >> 7, d = c2 & 127;
        Vr[((size_t)(b * cKVH + h) * cS + s) * cHD + d] = Y[yrow + col];
    }
}

// ---------------- flash attention: 128-row Q tile per block, 64-wide K/V tiles ----------------
// kbuf: K tile (64 x 128, stride 136) then reused as P tile (128 x 64, stride 72)
// vbuf: V^T tile (128 x 64, stride 72)
__global__ __launch_bounds__(256, 2) void flash_attn(const bf16* __restrict__ Q, const bf16* __restrict__ K,
                                                     const bf16* __restrict__ V, bf16* __restrict__ Ob) {
    __shared__ bf16 kbuf[9216];
    __shared__ bf16 vbuf[9216];
    const int tid = threadIdx.x;
    const int wave = tid >> 6, lane = tid & 63;
    const int quad = lane >> 4, l16 = lane & 15;
    const int qt = blockIdx.x, h = blockIdx.y, b = blockIdx.z;

    const bf16* Qg = Q + ((size_t)(b * cNH + h) * cS + qt * 128) * cHD;
    const bf16* Kg = K + (size_t)(b * cKVH + (h >> 2)) * cS * cHD;
    const bf16* Vg = V + (size_t)(b * cKVH + (h >> 2)) * cS * cHD;

    // Q fragments straight from global (wave's lanes collectively cover full rows)
    bf16x8 qf[2][4];
    #pragma unroll
    for (int i = 0; i < 2; ++i)
        #pragma unroll
        for (int ks = 0; ks < 4; ++ks)
            qf[i][ks] = *(const bf16x8*)(Qg + (size_t)(wave * 32 + i * 16 + l16) * cHD + ks * 32 + quad * 8);

    f32x4 oac[2][8];
    #pragma unroll
    for (int i = 0; i < 2; ++i)
        #pragma unroll
        for (int c = 0; c < 8; ++c) oac[i][c] = f32x4{0.f, 0.f, 0.f, 0.f};
    float mrow[2][4], lrow[2][4];
    #pragma unroll
    for (int i = 0; i < 2; ++i)
        #pragma unroll
        for (int r = 0; r < 4; ++r) { mrow[i][r] = -__builtin_inff(); lrow[i][r] = 0.f; }

    const int nkt = 2 * qt + 2;
    for (int kt = 0; kt < nkt; ++kt) {
        __syncthreads();  // previous iteration's LDS reads complete
        // stage K tile (64 rows x 128 d, stride 136) and V^T (d-major, stride 72)
        #pragma unroll
        for (int cc = 0; cc < 4; ++cc) {
            int g = cc * 256 + tid, row = g >> 4, c8 = g & 15;
            const bf16* src = Kg + (size_t)(kt * 64 + row) * cHD + c8 * 8;
            *(bf16x8*)&kbuf[row * 136 + c8 * 8] = *(const bf16x8*)src;
            bf16x8 vv = *(const bf16x8*)(Vg + (size_t)(kt * 64 + row) * cHD + c8 * 8);
            #pragma unroll
            for (int j = 0; j < 8; ++j) vbuf[(c8 * 8 + j) * 72 + row] = vv[j];
        }
        __syncthreads();
        // S = Q K^T  (per-wave rows 32w..32w+32, 64 cols)
        f32x4 sc[2][4];
        #pragma unroll
        for (int c = 0; c < 4; ++c) {
            bf16x8 kf[4];
            #pragma unroll
            for (int ks = 0; ks < 4; ++ks)
                kf[ks] = *(const bf16x8*)&kbuf[(c * 16 + l16) * 136 + ks * 32 + quad * 8];
            #pragma unroll
            for (int i = 0; i < 2; ++i) {
                f32x4 a = f32x4{0.f, 0.f, 0.f, 0.f};
                #pragma unroll
                for (int ks = 0; ks < 4; ++ks)
                    a = __builtin_amdgcn_mfma_f32_16x16x32_bf16(qf[i][ks], kf[ks], a, 0, 0, 0);
                sc[i][c] = a;
            }
        }
        const bool diag = (kt >= 2 * qt);
        const int rel = (kt - 2 * qt) * 64;
        // online softmax
        #pragma unroll
        for (int i = 0; i < 2; ++i) {
            #pragma unroll
            for (int r = 0; r < 4; ++r) {
                const int qrow = wave * 32 + i * 16 + quad * 4 + r;
                float mx = -__builtin_inff();
                #pragma unroll
                for (int c = 0; c < 4; ++c) {
                    float v = sc[i][c][r] * ATTN_SCALE;
                    if (diag && (rel + c * 16 + l16) > qrow) v = -1e9f;
                    sc[i][c][r] = v;
                    mx = fmaxf(mx, v);
                }
                #pragma unroll
                for (int off = 1; off < 16; off <<= 1) mx = fmaxf(mx, __shfl_xor(mx, off, 64));
                float mnew = fmaxf(mrow[i][r], mx);
                float alpha = __expf(mrow[i][r] - mnew);
                float rs = 0.f;
                #pragma unroll
                for (int c = 0; c < 4; ++c) {
                    float p = __expf(sc[i][c][r] - mnew);
                    sc[i][c][r] = p;
                    rs += p;
                }
                #pragma unroll
                for (int off = 1; off < 16; off <<= 1) rs += __shfl_xor(rs, off, 64);
                lrow[i][r] = lrow[i][r] * alpha + rs;
                mrow[i][r] = mnew;
                #pragma unroll
                for (int c = 0; c < 8; ++c) oac[i][c][r] *= alpha;
            }
        }
        __syncthreads();  // all waves done reading K
        // write P (bf16) into kbuf, stride 72
        #pragma unroll
        for (int i = 0; i < 2; ++i)
            #pragma unroll
            for (int c = 0; c < 4; ++c)
                #pragma unroll
                for (int r = 0; r < 4; ++r)
                    kbuf[(wave * 32 + i * 16 + quad * 4 + r) * 72 + c * 16 + l16] = (bf16)sc[i][c][r];
        __syncthreads();
        // O += P V
        bf16x8 pf[2][2];
        #pragma unroll
        for (int i = 0; i < 2; ++i)
            #pragma unroll
            for (int ks = 0; ks < 2; ++ks)
                pf[i][ks] = *(const bf16x8*)&kbuf[(wave * 32 + i * 16 + l16) * 72 + ks * 32 + quad * 8];
        #pragma unroll
        for (int cd = 0; cd < 8; ++cd) {
            bf16x8 vf[2];
            #pragma unroll
            for (int ks = 0; ks < 2; ++ks)
                vf[ks] = *(const bf16x8*)&vbuf[(cd * 16 + l16) * 72 + ks * 32 + quad * 8];
            #pragma unroll
            for (int i = 0; i < 2; ++i)
                #pragma unroll
                for (int ks = 0; ks < 2; ++ks)
                    oac[i][cd] = __builtin_amdgcn_mfma_f32_16x16x32_bf16(pf[i][ks], vf[ks], oac[i][cd], 0, 0, 0);
        }
    }
    // epilogue: normalize, write token-major (B*S, NH*HD) bf16
    #pragma unroll
    for (int i = 0; i < 2; ++i)
        #pragma unroll
        for (int cd = 0; cd < 8; ++cd)
            #pragma unroll
            for (int r = 0; r < 4; ++r) {
                int row = wave * 32 + i * 16 + quad * 4 + r;
                int d = cd * 16 + l16;
                float v = oac[i][cd][r] / lrow[i][r];
                Ob[((size_t)(b * cS + qt * 128 + row)) * (cNH * cHD) + h * cHD + d] = (bf16)v;
            }
}

extern "C" void kernel_launch(void* const* d_in, const int* in_sizes, int n_in,
                              void* d_out, int out_size, void* d_ws, size_t ws_size,
                              hipStream_t stream) {
    const float* x    = (const float*)d_in[0];
    const float* cosb = (const float*)d_in[1];
    const float* sinb = (const float*)d_in[2];
    // d_in[3] = attention_mask (exactly causal NEG) — implemented analytically
    const float* qw = (const float*)d_in[4];
    const float* kw = (const float*)d_in[5];
    const float* vw = (const float*)d_in[6];
    const float* qb = (const float*)d_in[7];
    const float* kb = (const float*)d_in[8];
    const float* vb = (const float*)d_in[9];
    const float* qA = (const float*)d_in[10];
    const float* qB = (const float*)d_in[11];
    const float* kA = (const float*)d_in[12];
    const float* kB = (const float*)d_in[13];
    const float* vA = (const float*)d_in[14];
    const float* vB = (const float*)d_in[15];
    const float* ow = (const float*)d_in[16];
    float* out = (float*)d_out;

    char* ws = (char*)d_ws;
    bf16* Xbf   = (bf16*)ws;  ws += (size_t)cNTOK * cH * 2;          // 16.8 MB
    bf16* Wc    = (bf16*)ws;  ws += (size_t)cNQKV * cH * 2;          // 12.6 MB
    float* biasc = (float*)ws; ws += (size_t)cNQKV * 4;              // 12 KB
    bf16* Yq    = (bf16*)ws;  ws += (size_t)cNTOK * cNQKV * 2;       // 25.2 MB
    bf16* Qr    = (bf16*)ws;  ws += (size_t)cB * cNH * cS * cHD * 2; // 16.8 MB
    bf16* Kr    = (bf16*)ws;  ws += (size_t)cB * cKVH * cS * cHD * 2;// 4.2 MB
    bf16* Vr    = (bf16*)ws;  ws += (size_t)cB * cKVH * cS * cHD * 2;// 4.2 MB
    bf16* OWbf  = (bf16*)ws;  ws += (size_t)cH * cH * 2;             // 8.4 MB
    bf16* Aout  = Yq;  // Yq is dead after rope_reorder; reuse for attention output

    conv_f32_bf16<<<(cNTOK * cH) / 1024, 256, 0, stream>>>(x, Xbf);
    conv_f32_bf16<<<(cH * cH) / 1024, 256, 0, stream>>>(ow, OWbf);
    prep_w<<<(cNQKV * cH) / 256, 256, 0, stream>>>(qw, kw, vw, qA, qB, kA, kB, vA, vB, Wc);
    prep_bias<<<(cNQKV + 255) / 256, 256, 0, stream>>>(qb, kb, vb, biasc);

    // QKV projection: (4096 x 3072) = X (4096x2048) @ Wc^T, + bias
    gemm_bt<0><<<dim3(cNQKV / 128, cNTOK / 128), 256, 0, stream>>>(Xbf, Wc, biasc, (void*)Yq, cNTOK, cNQKV, cH);

    rope_reorder<<<(cNTOK * cNQKV) / 256, 256, 0, stream>>>(Yq, cosb, sinb, Qr, Kr, Vr);

    flash_attn<<<dim3(cS / 128, cNH, cB), 256, 0, stream>>>(Qr, Kr, Vr, Aout);

    // output projection: (4096 x 2048) = Aout @ o_w^T, fp32 out
    gemm_bt<1><<<dim3(cH / 128, cNTOK / 128), 256, 0, stream>>>(Aout, OWbf, nullptr, (void*)out, cNTOK, cH, cH);
}

// Round 2
// 515.791 us; speedup vs baseline: 1.1718x; 1.1718x over previous
//
#include <hip/hip_runtime.h>

// Problem constants
constexpr int cB   = 2;
constexpr int cS   = 2048;
constexpr int cH   = 2048;
constexpr int cNH  = 16;
constexpr int cKVH = 4;
constexpr int cHD  = 128;
constexpr int cQD  = 2048;   // NH*HD
constexpr int cKVD = 512;    // KVH*HD
constexpr int cNQKV = 3072;  // QD + 2*KVD
constexpr int cNTOK = 4096;  // B*S
#define ATTN_SCALE 0.08838834764831845f

typedef __bf16 bf16;
typedef __attribute__((ext_vector_type(8))) __bf16 bf16x8;
typedef __attribute__((ext_vector_type(4))) __bf16 bf16x4;
typedef __attribute__((ext_vector_type(4))) float  f32x4;

__device__ __forceinline__ void async_load16(const bf16* g, bf16* l) {
    __builtin_amdgcn_global_load_lds(
        (const __attribute__((address_space(1))) void*)g,
        (__attribute__((address_space(3))) void*)l, 16, 0, 0);
}

// ---------------- fp32 -> bf16 convert (vectorized) ----------------
__global__ void conv_f32_bf16(const float* __restrict__ in, bf16* __restrict__ out) {
    int i = (blockIdx.x * 256 + threadIdx.x) * 4;
    f32x4 v = *(const f32x4*)(in + i);
    bf16x4 o;
    o[0] = (bf16)v[0]; o[1] = (bf16)v[1]; o[2] = (bf16)v[2]; o[3] = (bf16)v[3];
    *(bf16x4*)(out + i) = o;
}

// ---------------- fold LoRA into combined QKV weight (N=3072, K=2048), store (N,K) bf16 ----------------
__global__ void prep_w(const float* __restrict__ qw, const float* __restrict__ kw, const float* __restrict__ vw,
                       const float* __restrict__ qA, const float* __restrict__ qB,
                       const float* __restrict__ kA, const float* __restrict__ kB,
                       const float* __restrict__ vA, const float* __restrict__ vB,
                       bf16* __restrict__ Wc) {
    const int idx = blockIdx.x * 256 + threadIdx.x;   // < 3072*2048
    const int n = idx >> 11, k = idx & 2047;
    const float* W; const float* Am; const float* Bm; int nn, nd;
    if (n < cQD)             { W = qw; Am = qA; Bm = qB; nn = n;          nd = cQD; }
    else if (n < cQD + cKVD) { W = kw; Am = kA; Bm = kB; nn = n - cQD;    nd = cKVD; }
    else                     { W = vw; Am = vA; Bm = vB; nn = n - cQD - cKVD; nd = cKVD; }
    float acc = 0.f;
    #pragma unroll
    for (int r = 0; r < 16; ++r) acc += Am[k * 16 + r] * Bm[r * nd + nn];
    Wc[(size_t)n * cH + k] = (bf16)(W[(size_t)nn * cH + k] + 2.0f * acc);
}

__global__ void prep_bias(const float* __restrict__ qb, const float* __restrict__ kb,
                          const float* __restrict__ vb, float* __restrict__ biasc) {
    int n = blockIdx.x * 256 + threadIdx.x;
    if (n >= cNQKV) return;
    biasc[n] = (n < cQD) ? qb[n] : (n < cQD + cKVD ? kb[n - cQD] : vb[n - cQD - cKVD]);
}

// ---------------- 128x128-tile bf16 GEMM, B given as (N,K) ("B^T"), m97 structure ----------------
template <int OUTF32>
__global__ __launch_bounds__(256) void gemm_bt(const bf16* __restrict__ A, const bf16* __restrict__ Bw,
                                               const float* __restrict__ bias, void* __restrict__ Cp,
                                               int M, int N, int K) {
    __shared__ bf16 Al[128 * 32];
    __shared__ bf16 Bl[128 * 32];
    const int tid = threadIdx.x;
    const int wave = tid >> 6, lane = tid & 63;
    const int quad = lane >> 4, l16 = lane & 15;
    const int wr = wave >> 1, wc = wave & 1;
    const long bm = (long)blockIdx.y * 128, bn = (long)blockIdx.x * 128;

    f32x4 acc[4][4];
    #pragma unroll
    for (int i = 0; i < 4; ++i)
        #pragma unroll
        for (int c = 0; c < 4; ++c) acc[i][c] = f32x4{0.f, 0.f, 0.f, 0.f};

    const int r0 = lane >> 2;
    const int kc = (lane & 3) * 8;

    for (int k0 = 0; k0 < K; k0 += 32) {
        __syncthreads();
        #pragma unroll
        for (int j = 0; j < 2; ++j) {
            const int rb = (wave * 2 + j) * 16;
            const int row = rb + r0;
            async_load16(A  + (size_t)(bm + row) * K + k0 + kc, &Al[rb * 32 + r0 * 32 + kc]);
            async_load16(Bw + (size_t)(bn + row) * K + k0 + kc, &Bl[rb * 32 + r0 * 32 + kc]);
        }
        __syncthreads();
        bf16x8 af[4], bfr[4];
        #pragma unroll
        for (int i = 0; i < 4; ++i) af[i]  = *(const bf16x8*)&Al[(wr * 64 + i * 16 + l16) * 32 + quad * 8];
        #pragma unroll
        for (int c = 0; c < 4; ++c) bfr[c] = *(const bf16x8*)&Bl[(wc * 64 + c * 16 + l16) * 32 + quad * 8];
        #pragma unroll
        for (int i = 0; i < 4; ++i)
            #pragma unroll
            for (int c = 0; c < 4; ++c)
                acc[i][c] = __builtin_amdgcn_mfma_f32_16x16x32_bf16(af[i], bfr[c], acc[i][c], 0, 0, 0);
    }

    #pragma unroll
    for (int i = 0; i < 4; ++i)
        #pragma unroll
        for (int c = 0; c < 4; ++c) {
            const long m0 = bm + wr * 64 + i * 16 + quad * 4;
            const long n  = bn + wc * 64 + c * 16 + l16;
            #pragma unroll
            for (int r = 0; r < 4; ++r) {
                float v = acc[i][c][r];
                if (OUTF32) {
                    ((float*)Cp)[(m0 + r) * N + n] = v;
                } else {
                    v += bias[n];
                    ((bf16*)Cp)[(m0 + r) * N + n] = (bf16)v;
                }
            }
        }
}

// ---------------- RoPE + reorder to head-major Q/K (V handled by transpose_v) ----------------
__global__ void rope_reorder(const bf16* __restrict__ Y, const float* __restrict__ cosb,
                             const float* __restrict__ sinb,
                             bf16* __restrict__ Qr, bf16* __restrict__ Kr) {
    const int col = blockIdx.x * 256 + threadIdx.x;  // < 2560
    const int t = blockIdx.y;
    const int b = t >> 11, s = t & 2047;
    const size_t yrow = (size_t)t * cNQKV;
    const int d = col & 127;
    float y  = (float)Y[yrow + col];
    float pr = (d < 64) ? -(float)Y[yrow + col + 64] : (float)Y[yrow + col - 64];
    float cv = cosb[(size_t)t * cHD + d];
    float sv = sinb[(size_t)t * cHD + d];
    float o = y * cv + pr * sv;
    if (col < cQD) {
        int hh = col >> 7;
        Qr[((size_t)(b * cNH + hh) * cS + s) * cHD + d] = (bf16)o;
    } else {
        int hh = (col - cQD) >> 7;
        Kr[((size_t)(b * cKVH + hh) * cS + s) * cHD + d] = (bf16)o;
    }
}

// ---------------- transpose V columns of Yq -> Vt[b][kvh][d][s] ----------------
__global__ void transpose_v(const bf16* __restrict__ Yq, bf16* __restrict__ Vt) {
    __shared__ bf16 tile[64 * 72];
    const int tid = threadIdx.x;
    const int stile = blockIdx.x;        // 0..31
    const int y = blockIdx.y;            // 0..7
    const int b = blockIdx.z;
    const int kv = y >> 1, dh = y & 1;
    const int r = tid >> 3, c8 = tid & 7;
    #pragma unroll
    for (int it = 0; it < 2; ++it) {
        int row = it * 32 + r;
        const bf16* src = Yq + ((size_t)(b * cS + stile * 64 + row)) * cNQKV
                          + cQD + cKVD + kv * cHD + dh * 64 + c8 * 8;
        *(bf16x8*)&tile[row * 72 + c8 * 8] = *(const bf16x8*)src;
    }
    __syncthreads();
    #pragma unroll
    for (int it = 0; it < 2; ++it) {
        int dr = it * 32 + r;
        bf16x8 o;
        #pragma unroll
        for (int j = 0; j < 8; ++j) o[j] = tile[(c8 * 8 + j) * 72 + dr];
        bf16* dst = Vt + ((size_t)((b * cKVH + kv) * cHD) + dh * 64 + dr) * cS + stile * 64 + c8 * 8;
        *(bf16x8*)dst = o;
    }
}

// ---------------- flash attention v2: S^T/O^T orientation, swizzled LDS, async staging ----------------
// LDS: kb = K tile (64 seq x 128 d, 16B chunks XOR-swizzled), vb = V^T tile (128 d x 64 seq, swizzled),
//      pb = per-wave P (32 q x 64 seq, swizzled). 48 KB total -> 3 blocks/CU.
__global__ __launch_bounds__(256, 3) void flash2(const bf16* __restrict__ Q, const bf16* __restrict__ K,
                                                 const bf16* __restrict__ Vt, bf16* __restrict__ Ob) {
    __shared__ bf16 kb[8192];
    __shared__ bf16 vb[8192];
    __shared__ bf16 pb[8192];
    const int tid = threadIdx.x;
    const int wave = tid >> 6, lane = tid & 63;
    const int quad = lane >> 4, l16 = lane & 15;
    const int qt = (gridDim.x - 1) - blockIdx.x;   // heavy tiles dispatched first
    const int h = blockIdx.y, b = blockIdx.z;

    const bf16* Qg = Q  + ((size_t)(b * cNH + h) * cS + qt * 128) * cHD;
    const bf16* Kg = K  + (size_t)(b * cKVH + (h >> 2)) * cS * cHD;
    const bf16* Vg = Vt + (size_t)(b * cKVH + (h >> 2)) * cHD * cS;

    // Q B-fragments (lane l16 = q row, regs = d contiguous)
    bf16x8 qf[2][4];
    #pragma unroll
    for (int nt = 0; nt < 2; ++nt)
        #pragma unroll
        for (int ks = 0; ks < 4; ++ks)
            qf[nt][ks] = *(const bf16x8*)(Qg + (size_t)(wave * 32 + nt * 16 + l16) * cHD + ks * 32 + quad * 8);

    // staging offsets (elements), swizzle-inverted per lane slot
    int kgo[4], klo[4], vgo[4], vlo[4];
    #pragma unroll
    for (int i2 = 0; i2 < 4; ++i2) {
        const int si = i2 * 256 + tid;
        const int krow = si >> 4, kcsw = si & 15;
        const int kc = (kcsw & 8) | ((kcsw & 7) ^ (krow & 7));
        kgo[i2] = krow * cHD + kc * 8;
        klo[i2] = si * 8;
        const int vrow = si >> 3, vcsw = si & 7;
        const int vc = vcsw ^ (vrow & 7);
        vgo[i2] = vrow * cS + vc * 8;
        vlo[i2] = si * 8;
    }

    f32x4 oac[2][8];
    #pragma unroll
    for (int nt = 0; nt < 2; ++nt)
        #pragma unroll
        for (int dt = 0; dt < 8; ++dt) oac[nt][dt] = f32x4{0.f, 0.f, 0.f, 0.f};
    float m_[2] = {-3.0e38f, -3.0e38f}, l_[2] = {0.f, 0.f};

    const int nkt = 2 * qt + 2;
    for (int kt = 0; kt < nkt; ++kt) {
        __syncthreads();
        const bf16* Kt = Kg + (size_t)kt * 64 * cHD;
        const bf16* Vtt = Vg + kt * 64;
        #pragma unroll
        for (int i2 = 0; i2 < 4; ++i2) async_load16(Kt + kgo[i2], kb + klo[i2]);
        #pragma unroll
        for (int i2 = 0; i2 < 4; ++i2) async_load16(Vtt + vgo[i2], vb + vlo[i2]);
        __syncthreads();

        // S^T = K Q^T : st[nt][mt] rows = seq (quad*4+r), cols = q (l16)
        f32x4 st[2][4];
        #pragma unroll
        for (int mt = 0; mt < 4; ++mt) {
            bf16x8 kf[4];
            #pragma unroll
            for (int ks = 0; ks < 4; ++ks) {
                const int c = ks * 4 + quad;
                const int csw = (c & 8) | ((c & 7) ^ (l16 & 7));
                kf[ks] = *(const bf16x8*)&kb[(mt * 16 + l16) * 128 + csw * 8];
            }
            #pragma unroll
            for (int nt = 0; nt < 2; ++nt) {
                f32x4 a = f32x4{0.f, 0.f, 0.f, 0.f};
                #pragma unroll
                for (int ks = 0; ks < 4; ++ks)
                    a = __builtin_amdgcn_mfma_f32_16x16x32_bf16(kf[ks], qf[nt][ks], a, 0, 0, 0);
                st[nt][mt] = a;
            }
        }

        // online softmax per nt (all state in-lane: lane l16 = q row)
        #pragma unroll
        for (int nt = 0; nt < 2; ++nt) {
            const int qpos = qt * 128 + wave * 32 + nt * 16 + l16;
            const bool dm = (kt * 64 + 63) > (qt * 128 + wave * 32 + nt * 16);
            float tmax = -3.0e38f;
            #pragma unroll
            for (int mt = 0; mt < 4; ++mt)
                #pragma unroll
                for (int r = 0; r < 4; ++r) {
                    float v = st[nt][mt][r] * ATTN_SCALE;
                    if (dm) {
                        const int kpos = kt * 64 + mt * 16 + quad * 4 + r;
                        if (kpos > qpos) v = -3.0e38f;
                    }
                    st[nt][mt][r] = v;
                    tmax = fmaxf(tmax, v);
                }
            tmax = fmaxf(tmax, __shfl_xor(tmax, 16, 64));
            tmax = fmaxf(tmax, __shfl_xor(tmax, 32, 64));
            const float mnew = fmaxf(m_[nt], tmax);
            const float alpha = __expf(m_[nt] - mnew);
            m_[nt] = mnew;
            float rs = 0.f;
            #pragma unroll
            for (int mt = 0; mt < 4; ++mt)
                #pragma unroll
                for (int r = 0; r < 4; ++r) {
                    const float p = __expf(st[nt][mt][r] - mnew);
                    st[nt][mt][r] = p;
                    rs += p;
                }
            rs += __shfl_xor(rs, 16, 64);
            rs += __shfl_xor(rs, 32, 64);
            l_[nt] = l_[nt] * alpha + rs;
            #pragma unroll
            for (int dt = 0; dt < 8; ++dt)
                #pragma unroll
                for (int r = 0; r < 4; ++r) oac[nt][dt][r] *= alpha;
            // P write: pack 4 contiguous seq -> b64, swizzled (conflict-free)
            const int qrow = nt * 16 + l16;
            #pragma unroll
            for (int mt = 0; mt < 4; ++mt) {
                bf16x4 p4;
                #pragma unroll
                for (int r = 0; r < 4; ++r) p4[r] = (bf16)st[nt][mt][r];
                const int chunk = mt * 2 + (quad >> 1);
                const int csw = chunk ^ (l16 & 7);
                *(bf16x4*)&pb[wave * 2048 + qrow * 64 + csw * 8 + (quad & 1) * 4] = p4;
            }
        }

        // O^T += V^T P^T  (A = V^T frag, B = P frag)
        bf16x8 pf[2][2];
        #pragma unroll
        for (int nt = 0; nt < 2; ++nt)
            #pragma unroll
            for (int ks = 0; ks < 2; ++ks) {
                const int c = ks * 4 + quad;
                const int csw = c ^ (l16 & 7);
                pf[nt][ks] = *(const bf16x8*)&pb[wave * 2048 + (nt * 16 + l16) * 64 + csw * 8];
            }
        #pragma unroll
        for (int dt = 0; dt < 8; ++dt) {
            bf16x8 vf[2];
            #pragma unroll
            for (int ks = 0; ks < 2; ++ks) {
                const int c = ks * 4 + quad;
                const int csw = c ^ (l16 & 7);
                vf[ks] = *(const bf16x8*)&vb[(dt * 16 + l16) * 64 + csw * 8];
            }
            #pragma unroll
            for (int nt = 0; nt < 2; ++nt)
                #pragma unroll
                for (int ks = 0; ks < 2; ++ks)
                    oac[nt][dt] = __builtin_amdgcn_mfma_f32_16x16x32_bf16(vf[ks], pf[nt][ks], oac[nt][dt], 0, 0, 0);
        }
    }

    // epilogue: O^T C-layout -> lane l16 = token, regs = d contiguous -> b64 stores
    #pragma unroll
    for (int nt = 0; nt < 2; ++nt) {
        const float inv = 1.0f / l_[nt];
        const int token = qt * 128 + wave * 32 + nt * 16 + l16;
        bf16* orow = Ob + (size_t)(b * cS + token) * (cNH * cHD) + h * cHD;
        #pragma unroll
        for (int dt = 0; dt < 8; ++dt) {
            bf16x4 o4;
            #pragma unroll
            for (int r = 0; r < 4; ++r) o4[r] = (bf16)(oac[nt][dt][r] * inv);
            *(bf16x4*)&orow[dt * 16 + quad * 4] = o4;
        }
    }
}

extern "C" void kernel_launch(void* const* d_in, const int* in_sizes, int n_in,
                              void* d_out, int out_size, void* d_ws, size_t ws_size,
                              hipStream_t stream) {
    const float* x    = (const float*)d_in[0];
    const float* cosb = (const float*)d_in[1];
    const float* sinb = (const float*)d_in[2];
    // d_in[3] = attention_mask (exactly causal NEG) — implemented analytically
    const float* qw = (const float*)d_in[4];
    const float* kw = (const float*)d_in[5];
    const float* vw = (const float*)d_in[6];
    const float* qb = (const float*)d_in[7];
    const float* kb_ = (const float*)d_in[8];
    const float* vb = (const float*)d_in[9];
    const float* qA = (const float*)d_in[10];
    const float* qB = (const float*)d_in[11];
    const float* kA = (const float*)d_in[12];
    const float* kB = (const float*)d_in[13];
    const float* vA = (const float*)d_in[14];
    const float* vB = (const float*)d_in[15];
    const float* ow = (const float*)d_in[16];
    float* out = (float*)d_out;

    char* ws = (char*)d_ws;
    bf16* Xbf   = (bf16*)ws;  ws += (size_t)cNTOK * cH * 2;
    bf16* Wc    = (bf16*)ws;  ws += (size_t)cNQKV * cH * 2;
    float* biasc = (float*)ws; ws += (size_t)cNQKV * 4;
    bf16* Yq    = (bf16*)ws;  ws += (size_t)cNTOK * cNQKV * 2;
    bf16* Qr    = (bf16*)ws;  ws += (size_t)cB * cNH * cS * cHD * 2;
    bf16* Kr    = (bf16*)ws;  ws += (size_t)cB * cKVH * cS * cHD * 2;
    bf16* Vt    = (bf16*)ws;  ws += (size_t)cB * cKVH * cHD * cS * 2;
    bf16* OWbf  = (bf16*)ws;  ws += (size_t)cH * cH * 2;
    bf16* Aout  = Yq;  // Yq dead after rope_reorder + transpose_v

    conv_f32_bf16<<<(cNTOK * cH) / 1024, 256, 0, stream>>>(x, Xbf);
    conv_f32_bf16<<<(cH * cH) / 1024, 256, 0, stream>>>(ow, OWbf);
    prep_w<<<(cNQKV * cH) / 256, 256, 0, stream>>>(qw, kw, vw, qA, qB, kA, kB, vA, vB, Wc);
    prep_bias<<<(cNQKV + 255) / 256, 256, 0, stream>>>(qb, kb_, vb, biasc);

    gemm_bt<0><<<dim3(cNQKV / 128, cNTOK / 128), 256, 0, stream>>>(Xbf, Wc, biasc, (void*)Yq, cNTOK, cNQKV, cH);

    rope_reorder<<<dim3((cQD + cKVD) / 256, cNTOK), 256, 0, stream>>>(Yq, cosb, sinb, Qr, Kr);
    transpose_v<<<dim3(cS / 64, 8, cB), 256, 0, stream>>>(Yq, Vt);

    flash2<<<dim3(cS / 128, cNH, cB), 256, 0, stream>>>(Qr, Kr, Vt, Aout);

    gemm_bt<1><<<dim3(cH / 128, cNTOK / 128), 256, 0, stream>>>(Aout, OWbf, nullptr, (void*)out, cNTOK, cH, cH);
}

// Round 3
// 434.496 us; speedup vs baseline: 1.3911x; 1.1871x over previous
//
#include <hip/hip_runtime.h>

// Problem constants
constexpr int cB   = 2;
constexpr int cS   = 2048;
constexpr int cH   = 2048;
constexpr int cNH  = 16;
constexpr int cKVH = 4;
constexpr int cHD  = 128;
constexpr int cQD  = 2048;   // NH*HD
constexpr int cKVD = 512;    // KVH*HD
constexpr int cNQKV = 3072;  // QD + 2*KVD
constexpr int cNTOK = 4096;  // B*S
#define ATTN_SCALE 0.08838834764831845f

typedef __bf16 bf16;
typedef __attribute__((ext_vector_type(8))) __bf16 bf16x8;
typedef __attribute__((ext_vector_type(4))) __bf16 bf16x4;
typedef __attribute__((ext_vector_type(4))) float  f32x4;

__device__ __forceinline__ void async_load16(const bf16* g, bf16* l) {
    __builtin_amdgcn_global_load_lds(
        (const __attribute__((address_space(1))) void*)g,
        (__attribute__((address_space(3))) void*)l, 16, 0, 0);
}

// ---------------- fp32 -> bf16 convert (vectorized) ----------------
__global__ void conv_f32_bf16(const float* __restrict__ in, bf16* __restrict__ out) {
    int i = (blockIdx.x * 256 + threadIdx.x) * 4;
    f32x4 v = *(const f32x4*)(in + i);
    bf16x4 o;
    o[0] = (bf16)v[0]; o[1] = (bf16)v[1]; o[2] = (bf16)v[2]; o[3] = (bf16)v[3];
    *(bf16x4*)(out + i) = o;
}

// ---------------- fold LoRA into combined QKV weight (N=3072, K=2048), store (N,K) bf16 ----------------
__global__ void prep_w(const float* __restrict__ qw, const float* __restrict__ kw, const float* __restrict__ vw,
                       const float* __restrict__ qA, const float* __restrict__ qB,
                       const float* __restrict__ kA, const float* __restrict__ kB,
                       const float* __restrict__ vA, const float* __restrict__ vB,
                       bf16* __restrict__ Wc) {
    const int idx = blockIdx.x * 256 + threadIdx.x;   // < 3072*2048
    const int n = idx >> 11, k = idx & 2047;
    const float* W; const float* Am; const float* Bm; int nn, nd;
    if (n < cQD)             { W = qw; Am = qA; Bm = qB; nn = n;          nd = cQD; }
    else if (n < cQD + cKVD) { W = kw; Am = kA; Bm = kB; nn = n - cQD;    nd = cKVD; }
    else                     { W = vw; Am = vA; Bm = vB; nn = n - cQD - cKVD; nd = cKVD; }
    float acc = 0.f;
    #pragma unroll
    for (int r = 0; r < 16; ++r) acc += Am[k * 16 + r] * Bm[r * nd + nn];
    Wc[(size_t)n * cH + k] = (bf16)(W[(size_t)nn * cH + k] + 2.0f * acc);
}

__global__ void prep_bias(const float* __restrict__ qb, const float* __restrict__ kb,
                          const float* __restrict__ vb, float* __restrict__ biasc) {
    int n = blockIdx.x * 256 + threadIdx.x;
    if (n >= cNQKV) return;
    biasc[n] = (n < cQD) ? qb[n] : (n < cQD + cKVD ? kb[n - cQD] : vb[n - cQD - cKVD]);
}

// ---------------- 128x128-tile bf16 GEMM, B given as (N,K) ("B^T"), m97 structure ----------------
template <int OUTF32>
__global__ __launch_bounds__(256) void gemm_bt(const bf16* __restrict__ A, const bf16* __restrict__ Bw,
                                               const float* __restrict__ bias, void* __restrict__ Cp,
                                               int M, int N, int K) {
    __shared__ bf16 Al[128 * 32];
    __shared__ bf16 Bl[128 * 32];
    const int tid = threadIdx.x;
    const int wave = tid >> 6, lane = tid & 63;
    const int quad = lane >> 4, l16 = lane & 15;
    const int wr = wave >> 1, wc = wave & 1;
    const long bm = (long)blockIdx.y * 128, bn = (long)blockIdx.x * 128;

    f32x4 acc[4][4];
    #pragma unroll
    for (int i = 0; i < 4; ++i)
        #pragma unroll
        for (int c = 0; c < 4; ++c) acc[i][c] = f32x4{0.f, 0.f, 0.f, 0.f};

    const int r0 = lane >> 2;
    const int kc = (lane & 3) * 8;

    for (int k0 = 0; k0 < K; k0 += 32) {
        __syncthreads();
        #pragma unroll
        for (int j = 0; j < 2; ++j) {
            const int rb = (wave * 2 + j) * 16;
            const int row = rb + r0;
            async_load16(A  + (size_t)(bm + row) * K + k0 + kc, &Al[rb * 32 + r0 * 32 + kc]);
            async_load16(Bw + (size_t)(bn + row) * K + k0 + kc, &Bl[rb * 32 + r0 * 32 + kc]);
        }
        __syncthreads();
        bf16x8 af[4], bfr[4];
        #pragma unroll
        for (int i = 0; i < 4; ++i) af[i]  = *(const bf16x8*)&Al[(wr * 64 + i * 16 + l16) * 32 + quad * 8];
        #pragma unroll
        for (int c = 0; c < 4; ++c) bfr[c] = *(const bf16x8*)&Bl[(wc * 64 + c * 16 + l16) * 32 + quad * 8];
        #pragma unroll
        for (int i = 0; i < 4; ++i)
            #pragma unroll
            for (int c = 0; c < 4; ++c)
                acc[i][c] = __builtin_amdgcn_mfma_f32_16x16x32_bf16(af[i], bfr[c], acc[i][c], 0, 0, 0);
    }

    #pragma unroll
    for (int i = 0; i < 4; ++i)
        #pragma unroll
        for (int c = 0; c < 4; ++c) {
            const long m0 = bm + wr * 64 + i * 16 + quad * 4;
            const long n  = bn + wc * 64 + c * 16 + l16;
            #pragma unroll
            for (int r = 0; r < 4; ++r) {
                float v = acc[i][c][r];
                if (OUTF32) {
                    ((float*)Cp)[(m0 + r) * N + n] = v;
                } else {
                    v += bias[n];
                    ((bf16*)Cp)[(m0 + r) * N + n] = (bf16)v;
                }
            }
        }
}

// ---------------- RoPE + reorder to head-major Q/K; Q pre-scaled by ATTN_SCALE ----------------
// Exploits cos[d+64]==cos[d], sin[d+64]==sin[d]: each thread does the (d, d+64) pair.
__global__ void rope_reorder(const bf16* __restrict__ Y, const float* __restrict__ cosb,
                             const float* __restrict__ sinb,
                             bf16* __restrict__ Qr, bf16* __restrict__ Kr) {
    const int c = blockIdx.x * 256 + threadIdx.x;  // < 1280 = (NH+KVH)*64
    const int t = blockIdx.y;
    const int b = t >> 11, s = t & 2047;
    const int hh = c >> 6, dl = c & 63;
    const int col = hh * 128 + dl;
    const size_t yrow = (size_t)t * cNQKV;
    float y1 = (float)Y[yrow + col];
    float y2 = (float)Y[yrow + col + 64];
    float cv = cosb[(size_t)t * cHD + dl];
    float sv = sinb[(size_t)t * cHD + dl];
    float o1 = y1 * cv - y2 * sv;
    float o2 = y2 * cv + y1 * sv;
    if (hh < cNH) {
        o1 *= ATTN_SCALE; o2 *= ATTN_SCALE;
        bf16* dst = Qr + ((size_t)(b * cNH + hh) * cS + s) * cHD + dl;
        dst[0]  = (bf16)o1;
        dst[64] = (bf16)o2;
    } else {
        bf16* dst = Kr + ((size_t)(b * cKVH + (hh - cNH)) * cS + s) * cHD + dl;
        dst[0]  = (bf16)o1;
        dst[64] = (bf16)o2;
    }
}

// ---------------- transpose V columns of Yq -> Vt[b][kvh][d][s] ----------------
__global__ void transpose_v(const bf16* __restrict__ Yq, bf16* __restrict__ Vt) {
    __shared__ bf16 tile[64 * 72];
    const int tid = threadIdx.x;
    const int stile = blockIdx.x;        // 0..31
    const int y = blockIdx.y;            // 0..7
    const int b = blockIdx.z;
    const int kv = y >> 1, dh = y & 1;
    const int r = tid >> 3, c8 = tid & 7;
    #pragma unroll
    for (int it = 0; it < 2; ++it) {
        int row = it * 32 + r;
        const bf16* src = Yq + ((size_t)(b * cS + stile * 64 + row)) * cNQKV
                          + cQD + cKVD + kv * cHD + dh * 64 + c8 * 8;
        *(bf16x8*)&tile[row * 72 + c8 * 8] = *(const bf16x8*)src;
    }
    __syncthreads();
    #pragma unroll
    for (int it = 0; it < 2; ++it) {
        int dr = it * 32 + r;
        bf16x8 o;
        #pragma unroll
        for (int j = 0; j < 8; ++j) o[j] = tile[(c8 * 8 + j) * 72 + dr];
        bf16* dst = Vt + ((size_t)((b * cKVH + kv) * cHD) + dh * 64 + dr) * cS + stile * 64 + c8 * 8;
        *(bf16x8*)dst = o;
    }
}

// ---------------- flash attention v3: Q-tile 64, K-tile 64, 40KB LDS -> 4 blocks/CU ----------------
// Each wave owns 16 q rows. kb = K tile (64 x 128, swizzled), vb = V^T (128 x 64, swizzled),
// pb = per-wave P (16 q x 64 seq, swizzled). Q pre-scaled by ATTN_SCALE at RoPE.
__global__ __launch_bounds__(256, 4) void flash3(const bf16* __restrict__ Q, const bf16* __restrict__ K,
                                                 const bf16* __restrict__ Vt, bf16* __restrict__ Ob) {
    __shared__ bf16 kb[8192];
    __shared__ bf16 vb[8192];
    __shared__ bf16 pb[4096];
    const int tid = threadIdx.x;
    const int wave = tid >> 6, lane = tid & 63;
    const int quad = lane >> 4, l16 = lane & 15;
    const int qt = (gridDim.x - 1) - blockIdx.x;   // heavy tiles first
    const int h = blockIdx.y, b = blockIdx.z;

    const bf16* Qg = Q  + ((size_t)(b * cNH + h) * cS + qt * 64) * cHD;
    const bf16* Kg = K  + (size_t)(b * cKVH + (h >> 2)) * cS * cHD;
    const bf16* Vg = Vt + (size_t)(b * cKVH + (h >> 2)) * cHD * cS;

    // Q B-fragments: lane l16 = q row (wave*16+l16), regs = d contiguous
    bf16x8 qf[4];
    #pragma unroll
    for (int ks = 0; ks < 4; ++ks)
        qf[ks] = *(const bf16x8*)(Qg + (size_t)(wave * 16 + l16) * cHD + ks * 32 + quad * 8);

    // staging offsets, swizzle-inverted per lane slot
    int kgo[4], vgo[4], slo[4];
    #pragma unroll
    for (int i2 = 0; i2 < 4; ++i2) {
        const int si = i2 * 256 + tid;
        const int krow = si >> 4, kcsw = si & 15;
        const int kc = (kcsw & 8) | ((kcsw & 7) ^ (krow & 7));
        kgo[i2] = krow * cHD + kc * 8;
        const int vrow = si >> 3, vcsw = si & 7;
        const int vc = vcsw ^ (vrow & 7);
        vgo[i2] = vrow * cS + vc * 8;
        slo[i2] = si * 8;
    }

    f32x4 oac[8];
    #pragma unroll
    for (int dt = 0; dt < 8; ++dt) oac[dt] = f32x4{0.f, 0.f, 0.f, 0.f};
    float m_ = -3.0e38f, l_ = 0.f;

    const int nkt = qt + 1;
    for (int kt = 0; kt < nkt; ++kt) {
        __syncthreads();
        const bf16* Kt  = Kg + (size_t)kt * 64 * cHD;
        const bf16* Vtt = Vg + kt * 64;
        #pragma unroll
        for (int i2 = 0; i2 < 4; ++i2) async_load16(Kt + kgo[i2], kb + slo[i2]);
        #pragma unroll
        for (int i2 = 0; i2 < 4; ++i2) async_load16(Vtt + vgo[i2], vb + slo[i2]);
        __syncthreads();

        // S^T = K Q^T : st[mt] rows = seq (quad*4+r), cols = q (l16)
        f32x4 st[4];
        #pragma unroll
        for (int mt = 0; mt < 4; ++mt) {
            bf16x8 kf[4];
            #pragma unroll
            for (int ks = 0; ks < 4; ++ks) {
                const int c = ks * 4 + quad;
                const int csw = (c & 8) | ((c & 7) ^ (l16 & 7));
                kf[ks] = *(const bf16x8*)&kb[(mt * 16 + l16) * 128 + csw * 8];
            }
            f32x4 a = f32x4{0.f, 0.f, 0.f, 0.f};
            #pragma unroll
            for (int ks = 0; ks < 4; ++ks)
                a = __builtin_amdgcn_mfma_f32_16x16x32_bf16(kf[ks], qf[ks], a, 0, 0, 0);
            st[mt] = a;
        }

        // online softmax (all state in-lane: lane l16 = q row)
        const int qpos = qt * 64 + wave * 16 + l16;
        const bool dm = (kt * 64 + 63) > (qt * 64 + wave * 16);
        float tmax = -3.0e38f;
        #pragma unroll
        for (int mt = 0; mt < 4; ++mt)
            #pragma unroll
            for (int r = 0; r < 4; ++r) {
                float v = st[mt][r];
                if (dm) {
                    const int kpos = kt * 64 + mt * 16 + quad * 4 + r;
                    if (kpos > qpos) v = -3.0e38f;
                }
                st[mt][r] = v;
                tmax = fmaxf(tmax, v);
            }
        tmax = fmaxf(tmax, __shfl_xor(tmax, 16, 64));
        tmax = fmaxf(tmax, __shfl_xor(tmax, 32, 64));
        const float mnew = fmaxf(m_, tmax);
        const float alpha = __expf(m_ - mnew);
        m_ = mnew;
        float rs = 0.f;
        #pragma unroll
        for (int mt = 0; mt < 4; ++mt)
            #pragma unroll
            for (int r = 0; r < 4; ++r) {
                const float p = __expf(st[mt][r] - mnew);
                st[mt][r] = p;
                rs += p;
            }
        rs += __shfl_xor(rs, 16, 64);
        rs += __shfl_xor(rs, 32, 64);
        l_ = l_ * alpha + rs;
        #pragma unroll
        for (int dt = 0; dt < 8; ++dt)
            #pragma unroll
            for (int r = 0; r < 4; ++r) oac[dt][r] *= alpha;

        // P write into per-wave pb region (no barrier needed; wave-private)
        #pragma unroll
        for (int mt = 0; mt < 4; ++mt) {
            bf16x4 p4;
            #pragma unroll
            for (int r = 0; r < 4; ++r) p4[r] = (bf16)st[mt][r];
            const int csw = (mt * 2 + (quad >> 1)) ^ (l16 & 7);
            *(bf16x4*)&pb[wave * 1024 + l16 * 64 + csw * 8 + (quad & 1) * 4] = p4;
        }

        // O^T += V^T P^T
        bf16x8 pf[2];
        #pragma unroll
        for (int ks = 0; ks < 2; ++ks) {
            const int c = ks * 4 + quad;
            const int csw = c ^ (l16 & 7);
            pf[ks] = *(const bf16x8*)&pb[wave * 1024 + l16 * 64 + csw * 8];
        }
        #pragma unroll
        for (int dt = 0; dt < 8; ++dt) {
            bf16x8 vf[2];
            #pragma unroll
            for (int ks = 0; ks < 2; ++ks) {
                const int c = ks * 4 + quad;
                const int csw = c ^ (l16 & 7);
                vf[ks] = *(const bf16x8*)&vb[(dt * 16 + l16) * 64 + csw * 8];
            }
            #pragma unroll
            for (int ks = 0; ks < 2; ++ks)
                oac[dt] = __builtin_amdgcn_mfma_f32_16x16x32_bf16(vf[ks], pf[ks], oac[dt], 0, 0, 0);
        }
    }

    // epilogue: lane l16 = token, regs = d contiguous -> b64 stores
    const float inv = 1.0f / l_;
    const int token = qt * 64 + wave * 16 + l16;
    bf16* orow = Ob + (size_t)(b * cS + token) * (cNH * cHD) + h * cHD;
    #pragma unroll
    for (int dt = 0; dt < 8; ++dt) {
        bf16x4 o4;
        #pragma unroll
        for (int r = 0; r < 4; ++r) o4[r] = (bf16)(oac[dt][r] * inv);
        *(bf16x4*)&orow[dt * 16 + quad * 4] = o4;
    }
}

extern "C" void kernel_launch(void* const* d_in, const int* in_sizes, int n_in,
                              void* d_out, int out_size, void* d_ws, size_t ws_size,
                              hipStream_t stream) {
    const float* x    = (const float*)d_in[0];
    const float* cosb = (const float*)d_in[1];
    const float* sinb = (const float*)d_in[2];
    // d_in[3] = attention_mask (exactly causal NEG) — implemented analytically
    const float* qw = (const float*)d_in[4];
    const float* kw = (const float*)d_in[5];
    const float* vw = (const float*)d_in[6];
    const float* qb = (const float*)d_in[7];
    const float* kb_ = (const float*)d_in[8];
    const float* vb = (const float*)d_in[9];
    const float* qA = (const float*)d_in[10];
    const float* qB = (const float*)d_in[11];
    const float* kA = (const float*)d_in[12];
    const float* kB = (const float*)d_in[13];
    const float* vA = (const float*)d_in[14];
    const float* vB = (const float*)d_in[15];
    const float* ow = (const float*)d_in[16];
    float* out = (float*)d_out;

    char* ws = (char*)d_ws;
    bf16* Xbf   = (bf16*)ws;  ws += (size_t)cNTOK * cH * 2;
    bf16* Wc    = (bf16*)ws;  ws += (size_t)cNQKV * cH * 2;
    float* biasc = (float*)ws; ws += (size_t)cNQKV * 4;
    bf16* Yq    = (bf16*)ws;  ws += (size_t)cNTOK * cNQKV * 2;
    bf16* Qr    = (bf16*)ws;  ws += (size_t)cB * cNH * cS * cHD * 2;
    bf16* Kr    = (bf16*)ws;  ws += (size_t)cB * cKVH * cS * cHD * 2;
    bf16* Vt    = (bf16*)ws;  ws += (size_t)cB * cKVH * cHD * cS * 2;
    bf16* OWbf  = (bf16*)ws;  ws += (size_t)cH * cH * 2;
    bf16* Aout  = Yq;  // Yq dead after rope_reorder + transpose_v

    conv_f32_bf16<<<(cNTOK * cH) / 1024, 256, 0, stream>>>(x, Xbf);
    conv_f32_bf16<<<(cH * cH) / 1024, 256, 0, stream>>>(ow, OWbf);
    prep_w<<<(cNQKV * cH) / 256, 256, 0, stream>>>(qw, kw, vw, qA, qB, kA, kB, vA, vB, Wc);
    prep_bias<<<(cNQKV + 255) / 256, 256, 0, stream>>>(qb, kb_, vb, biasc);

    gemm_bt<0><<<dim3(cNQKV / 128, cNTOK / 128), 256, 0, stream>>>(Xbf, Wc, biasc, (void*)Yq, cNTOK, cNQKV, cH);

    rope_reorder<<<dim3(5, cNTOK), 256, 0, stream>>>(Yq, cosb, sinb, Qr, Kr);
    transpose_v<<<dim3(cS / 64, 8, cB), 256, 0, stream>>>(Yq, Vt);

    flash3<<<dim3(cS / 64, cNH, cB), 256, 0, stream>>>(Qr, Kr, Vt, Aout);

    gemm_bt<1><<<dim3(cH / 128, cNTOK / 128), 256, 0, stream>>>(Aout, OWbf, nullptr, (void*)out, cNTOK, cH, cH);
}

// Round 4
// 406.803 us; speedup vs baseline: 1.4858x; 1.0681x over previous
//
#include <hip/hip_runtime.h>

// Problem constants
constexpr int cB   = 2;
constexpr int cS   = 2048;
constexpr int cH   = 2048;
constexpr int cNH  = 16;
constexpr int cKVH = 4;
constexpr int cHD  = 128;
constexpr int cQD  = 2048;   // NH*HD
constexpr int cKVD = 512;    // KVH*HD
constexpr int cNQKV = 3072;  // QD + 2*KVD
constexpr int cNTOK = 4096;  // B*S
#define ATTN_SCALE 0.08838834764831845f

typedef __bf16 bf16;
typedef __attribute__((ext_vector_type(8))) __bf16 bf16x8;
typedef __attribute__((ext_vector_type(4))) __bf16 bf16x4;
typedef __attribute__((ext_vector_type(4))) float  f32x4;

__device__ __forceinline__ void async_load16(const bf16* g, bf16* l) {
    __builtin_amdgcn_global_load_lds(
        (const __attribute__((address_space(1))) void*)g,
        (__attribute__((address_space(3))) void*)l, 16, 0, 0);
}

// ---------------- fp32 -> bf16 convert (vectorized) ----------------
__global__ void conv_f32_bf16(const float* __restrict__ in, bf16* __restrict__ out) {
    int i = (blockIdx.x * 256 + threadIdx.x) * 4;
    f32x4 v = *(const f32x4*)(in + i);
    bf16x4 o;
    o[0] = (bf16)v[0]; o[1] = (bf16)v[1]; o[2] = (bf16)v[2]; o[3] = (bf16)v[3];
    *(bf16x4*)(out + i) = o;
}

// ---------------- fold LoRA into combined QKV weight (N=3072, K=2048), store (N,K) bf16 ----------------
__global__ void prep_w(const float* __restrict__ qw, const float* __restrict__ kw, const float* __restrict__ vw,
                       const float* __restrict__ qA, const float* __restrict__ qB,
                       const float* __restrict__ kA, const float* __restrict__ kB,
                       const float* __restrict__ vA, const float* __restrict__ vB,
                       bf16* __restrict__ Wc) {
    const int idx = blockIdx.x * 256 + threadIdx.x;   // < 3072*2048
    const int n = idx >> 11, k = idx & 2047;
    const float* W; const float* Am; const float* Bm; int nn, nd;
    if (n < cQD)             { W = qw; Am = qA; Bm = qB; nn = n;          nd = cQD; }
    else if (n < cQD + cKVD) { W = kw; Am = kA; Bm = kB; nn = n - cQD;    nd = cKVD; }
    else                     { W = vw; Am = vA; Bm = vB; nn = n - cQD - cKVD; nd = cKVD; }
    float acc = 0.f;
    #pragma unroll
    for (int r = 0; r < 16; ++r) acc += Am[k * 16 + r] * Bm[r * nd + nn];
    Wc[(size_t)n * cH + k] = (bf16)(W[(size_t)nn * cH + k] + 2.0f * acc);
}

__global__ void prep_bias(const float* __restrict__ qb, const float* __restrict__ kb,
                          const float* __restrict__ vb, float* __restrict__ biasc) {
    int n = blockIdx.x * 256 + threadIdx.x;
    if (n >= cNQKV) return;
    biasc[n] = (n < cQD) ? qb[n] : (n < cQD + cKVD ? kb[n - cQD] : vb[n - cQD - cKVD]);
}

// ---------------- QKV GEMM with fused bias + RoPE + head-reorder + V-transpose epilogue ----------------
// 128x128 tile; N-tile == one head (128 cols). B-frag column remap so each wave
// holds both RoPE partners (d, d+64): n(c) = wc*32 + (c&1)*16 + (c>>1)*64 + l16.
__global__ __launch_bounds__(256) void gemm_qkv(const bf16* __restrict__ A, const bf16* __restrict__ Bw,
                                                const float* __restrict__ bias,
                                                const float* __restrict__ cosb, const float* __restrict__ sinb,
                                                bf16* __restrict__ Qr, bf16* __restrict__ Kr,
                                                bf16* __restrict__ Vt) {
    __shared__ bf16 Al[128 * 32];
    __shared__ bf16 Bl[128 * 32];
    const int tid = threadIdx.x;
    const int wave = tid >> 6, lane = tid & 63;
    const int quad = lane >> 4, l16 = lane & 15;
    const int wr = wave >> 1, wc = wave & 1;
    const long bm = (long)blockIdx.y * 128, bn = (long)blockIdx.x * 128;
    const int K = cH;

    f32x4 acc[4][4];
    #pragma unroll
    for (int i = 0; i < 4; ++i)
        #pragma unroll
        for (int c = 0; c < 4; ++c) acc[i][c] = f32x4{0.f, 0.f, 0.f, 0.f};

    const int r0 = lane >> 2;
    const int kc = (lane & 3) * 8;

    for (int k0 = 0; k0 < K; k0 += 32) {
        __syncthreads();
        #pragma unroll
        for (int j = 0; j < 2; ++j) {
            const int rb = (wave * 2 + j) * 16;
            const int row = rb + r0;
            async_load16(A  + (size_t)(bm + row) * K + k0 + kc, &Al[rb * 32 + r0 * 32 + kc]);
            async_load16(Bw + (size_t)(bn + row) * K + k0 + kc, &Bl[rb * 32 + r0 * 32 + kc]);
        }
        __syncthreads();
        bf16x8 af[4], bfr[4];
        #pragma unroll
        for (int i = 0; i < 4; ++i) af[i]  = *(const bf16x8*)&Al[(wr * 64 + i * 16 + l16) * 32 + quad * 8];
        #pragma unroll
        for (int c = 0; c < 4; ++c) {
            const int nrow = wc * 32 + (c & 1) * 16 + (c >> 1) * 64 + l16;
            bfr[c] = *(const bf16x8*)&Bl[nrow * 32 + quad * 8];
        }
        #pragma unroll
        for (int i = 0; i < 4; ++i)
            #pragma unroll
            for (int c = 0; c < 4; ++c)
                acc[i][c] = __builtin_amdgcn_mfma_f32_16x16x32_bf16(af[i], bfr[c], acc[i][c], 0, 0, 0);
    }

    // bias add (n per fragment column set)
    #pragma unroll
    for (int c = 0; c < 4; ++c) {
        const int nloc = wc * 32 + (c & 1) * 16 + (c >> 1) * 64 + l16;
        const float bv = bias[bn + nloc];
        #pragma unroll
        for (int i = 0; i < 4; ++i)
            #pragma unroll
            for (int r = 0; r < 4; ++r) acc[i][c][r] += bv;
    }

    const int head = (int)(bn >> 7);   // 0..23: 16 Q, 4 K, 4 V
    if (head < cNH + cKVH) {
        // RoPE + store head-major
        const bool isQ = head < cNH;
        #pragma unroll
        for (int cl = 0; cl < 2; ++cl) {
            const int d = wc * 32 + cl * 16 + l16;   // 0..63
            #pragma unroll
            for (int i = 0; i < 4; ++i)
                #pragma unroll
                for (int r = 0; r < 4; ++r) {
                    const long t = bm + wr * 64 + i * 16 + quad * 4 + r;  // global token
                    const float cv = cosb[t * cHD + d];
                    const float sv = sinb[t * cHD + d];
                    const float v1 = acc[i][cl][r], v2 = acc[i][cl + 2][r];
                    float o1 = v1 * cv - v2 * sv;
                    float o2 = v2 * cv + v1 * sv;
                    if (isQ) { o1 *= ATTN_SCALE; o2 *= ATTN_SCALE; }
                    const int b = (int)(t >> 11), s = (int)(t & 2047);
                    bf16* dst = isQ
                        ? Qr + ((size_t)(b * cNH + head) * cS + s) * cHD
                        : Kr + ((size_t)(b * cKVH + (head - cNH)) * cS + s) * cHD;
                    dst[d]      = (bf16)o1;
                    dst[d + 64] = (bf16)o2;
                }
        }
    } else {
        // V: transpose into Vt[b][kvh][d][s] (4 consecutive s -> b64 store)
        const int kv = head - cNH - cKVH;
        const int b = (int)(bm >> 11);
        const int sbase = (int)(bm & 2047);
        #pragma unroll
        for (int c = 0; c < 4; ++c) {
            const int d = wc * 32 + (c & 1) * 16 + (c >> 1) * 64 + l16;
            #pragma unroll
            for (int i = 0; i < 4; ++i) {
                const int s0 = sbase + wr * 64 + i * 16 + quad * 4;
                bf16x4 o4;
                #pragma unroll
                for (int r = 0; r < 4; ++r) o4[r] = (bf16)acc[i][c][r];
                *(bf16x4*)&Vt[((size_t)((b * cKVH + kv) * cHD) + d) * cS + s0] = o4;
            }
        }
    }
}

// ---------------- plain 128x128-tile bf16 GEMM, fp32 out (output projection) ----------------
__global__ __launch_bounds__(256) void gemm_bt_f32(const bf16* __restrict__ A, const bf16* __restrict__ Bw,
                                                   float* __restrict__ Cp, int M, int N, int K) {
    __shared__ bf16 Al[128 * 32];
    __shared__ bf16 Bl[128 * 32];
    const int tid = threadIdx.x;
    const int wave = tid >> 6, lane = tid & 63;
    const int quad = lane >> 4, l16 = lane & 15;
    const int wr = wave >> 1, wc = wave & 1;
    const long bm = (long)blockIdx.y * 128, bn = (long)blockIdx.x * 128;

    f32x4 acc[4][4];
    #pragma unroll
    for (int i = 0; i < 4; ++i)
        #pragma unroll
        for (int c = 0; c < 4; ++c) acc[i][c] = f32x4{0.f, 0.f, 0.f, 0.f};

    const int r0 = lane >> 2;
    const int kc = (lane & 3) * 8;

    for (int k0 = 0; k0 < K; k0 += 32) {
        __syncthreads();
        #pragma unroll
        for (int j = 0; j < 2; ++j) {
            const int rb = (wave * 2 + j) * 16;
            const int row = rb + r0;
            async_load16(A  + (size_t)(bm + row) * K + k0 + kc, &Al[rb * 32 + r0 * 32 + kc]);
            async_load16(Bw + (size_t)(bn + row) * K + k0 + kc, &Bl[rb * 32 + r0 * 32 + kc]);
        }
        __syncthreads();
        bf16x8 af[4], bfr[4];
        #pragma unroll
        for (int i = 0; i < 4; ++i) af[i]  = *(const bf16x8*)&Al[(wr * 64 + i * 16 + l16) * 32 + quad * 8];
        #pragma unroll
        for (int c = 0; c < 4; ++c) bfr[c] = *(const bf16x8*)&Bl[(wc * 64 + c * 16 + l16) * 32 + quad * 8];
        #pragma unroll
        for (int i = 0; i < 4; ++i)
            #pragma unroll
            for (int c = 0; c < 4; ++c)
                acc[i][c] = __builtin_amdgcn_mfma_f32_16x16x32_bf16(af[i], bfr[c], acc[i][c], 0, 0, 0);
    }

    #pragma unroll
    for (int i = 0; i < 4; ++i)
        #pragma unroll
        for (int c = 0; c < 4; ++c) {
            const long m0 = bm + wr * 64 + i * 16 + quad * 4;
            const long n  = bn + wc * 64 + c * 16 + l16;
            #pragma unroll
            for (int r = 0; r < 4; ++r)
                Cp[(m0 + r) * N + n] = acc[i][c][r];
        }
}

// ---------------- flash attention v4: paired q-tiles (perfect balance), Q-tile 64 ----------------
// Block pi handles q-tiles (31-pi) then pi: exactly 33 iterations each. Grid 512 = 2 blocks/CU.
__global__ __launch_bounds__(256, 2) void flash4(const bf16* __restrict__ Q, const bf16* __restrict__ K,
                                                 const bf16* __restrict__ Vt, bf16* __restrict__ Ob) {
    __shared__ bf16 kb[8192];
    __shared__ bf16 vb[8192];
    __shared__ bf16 pb[4096];
    const int tid = threadIdx.x;
    const int wave = tid >> 6, lane = tid & 63;
    const int quad = lane >> 4, l16 = lane & 15;
    const int pi = blockIdx.x;               // 0..15
    const int h = blockIdx.y, b = blockIdx.z;

    const bf16* Qh = Q  + (size_t)(b * cNH + h) * cS * cHD;
    const bf16* Kg = K  + (size_t)(b * cKVH + (h >> 2)) * cS * cHD;
    const bf16* Vg = Vt + (size_t)(b * cKVH + (h >> 2)) * cHD * cS;

    // staging offsets, swizzle-inverted per lane slot (computed once)
    int kgo[4], vgo[4], slo[4];
    #pragma unroll
    for (int i2 = 0; i2 < 4; ++i2) {
        const int si = i2 * 256 + tid;
        const int krow = si >> 4, kcsw = si & 15;
        const int kc = (kcsw & 8) | ((kcsw & 7) ^ (krow & 7));
        kgo[i2] = krow * cHD + kc * 8;
        const int vrow = si >> 3, vcsw = si & 7;
        const int vc = vcsw ^ (vrow & 7);
        vgo[i2] = vrow * cS + vc * 8;
        slo[i2] = si * 8;
    }

    #pragma unroll
    for (int t2 = 0; t2 < 2; ++t2) {
        const int qt = t2 == 0 ? (31 - pi) : pi;

        const bf16* Qg = Qh + (size_t)qt * 64 * cHD;
        bf16x8 qf[4];
        #pragma unroll
        for (int ks = 0; ks < 4; ++ks)
            qf[ks] = *(const bf16x8*)(Qg + (size_t)(wave * 16 + l16) * cHD + ks * 32 + quad * 8);

        f32x4 oac[8];
        #pragma unroll
        for (int dt = 0; dt < 8; ++dt) oac[dt] = f32x4{0.f, 0.f, 0.f, 0.f};
        float m_ = -3.0e38f, l_ = 0.f;

        const int nkt = qt + 1;
        for (int kt = 0; kt < nkt; ++kt) {
            __syncthreads();
            const bf16* Kt  = Kg + (size_t)kt * 64 * cHD;
            const bf16* Vtt = Vg + kt * 64;
            #pragma unroll
            for (int i2 = 0; i2 < 4; ++i2) async_load16(Kt + kgo[i2], kb + slo[i2]);
            #pragma unroll
            for (int i2 = 0; i2 < 4; ++i2) async_load16(Vtt + vgo[i2], vb + slo[i2]);
            __syncthreads();

            // S^T = K Q^T : st[mt] rows = seq (quad*4+r), cols = q (l16)
            f32x4 st[4];
            #pragma unroll
            for (int mt = 0; mt < 4; ++mt) {
                bf16x8 kf[4];
                #pragma unroll
                for (int ks = 0; ks < 4; ++ks) {
                    const int c = ks * 4 + quad;
                    const int csw = (c & 8) | ((c & 7) ^ (l16 & 7));
                    kf[ks] = *(const bf16x8*)&kb[(mt * 16 + l16) * 128 + csw * 8];
                }
                f32x4 a = f32x4{0.f, 0.f, 0.f, 0.f};
                #pragma unroll
                for (int ks = 0; ks < 4; ++ks)
                    a = __builtin_amdgcn_mfma_f32_16x16x32_bf16(kf[ks], qf[ks], a, 0, 0, 0);
                st[mt] = a;
            }

            // online softmax (all state in-lane: lane l16 = q row)
            const int qpos = qt * 64 + wave * 16 + l16;
            const bool dm = (kt * 64 + 63) > (qt * 64 + wave * 16);
            float tmax = -3.0e38f;
            #pragma unroll
            for (int mt = 0; mt < 4; ++mt)
                #pragma unroll
                for (int r = 0; r < 4; ++r) {
                    float v = st[mt][r];
                    if (dm) {
                        const int kpos = kt * 64 + mt * 16 + quad * 4 + r;
                        if (kpos > qpos) v = -3.0e38f;
                    }
                    st[mt][r] = v;
                    tmax = fmaxf(tmax, v);
                }
            tmax = fmaxf(tmax, __shfl_xor(tmax, 16, 64));
            tmax = fmaxf(tmax, __shfl_xor(tmax, 32, 64));
            const float mnew = fmaxf(m_, tmax);
            const float alpha = __expf(m_ - mnew);
            m_ = mnew;
            float rs = 0.f;
            #pragma unroll
            for (int mt = 0; mt < 4; ++mt)
                #pragma unroll
                for (int r = 0; r < 4; ++r) {
                    const float p = __expf(st[mt][r] - mnew);
                    st[mt][r] = p;
                    rs += p;
                }
            rs += __shfl_xor(rs, 16, 64);
            rs += __shfl_xor(rs, 32, 64);
            l_ = l_ * alpha + rs;
            #pragma unroll
            for (int dt = 0; dt < 8; ++dt)
                #pragma unroll
                for (int r = 0; r < 4; ++r) oac[dt][r] *= alpha;

            // P write into per-wave pb region (wave-private, no barrier)
            #pragma unroll
            for (int mt = 0; mt < 4; ++mt) {
                bf16x4 p4;
                #pragma unroll
                for (int r = 0; r < 4; ++r) p4[r] = (bf16)st[mt][r];
                const int csw = (mt * 2 + (quad >> 1)) ^ (l16 & 7);
                *(bf16x4*)&pb[wave * 1024 + l16 * 64 + csw * 8 + (quad & 1) * 4] = p4;
            }

            // O^T += V^T P^T
            bf16x8 pf[2];
            #pragma unroll
            for (int ks = 0; ks < 2; ++ks) {
                const int c = ks * 4 + quad;
                const int csw = c ^ (l16 & 7);
                pf[ks] = *(const bf16x8*)&pb[wave * 1024 + l16 * 64 + csw * 8];
            }
            #pragma unroll
            for (int dt = 0; dt < 8; ++dt) {
                bf16x8 vf[2];
                #pragma unroll
                for (int ks = 0; ks < 2; ++ks) {
                    const int c = ks * 4 + quad;
                    const int csw = c ^ (l16 & 7);
                    vf[ks] = *(const bf16x8*)&vb[(dt * 16 + l16) * 64 + csw * 8];
                }
                #pragma unroll
                for (int ks = 0; ks < 2; ++ks)
                    oac[dt] = __builtin_amdgcn_mfma_f32_16x16x32_bf16(vf[ks], pf[ks], oac[dt], 0, 0, 0);
            }
        }

        // epilogue: lane l16 = token, regs = d contiguous -> b64 stores
        const float inv = 1.0f / l_;
        const int token = qt * 64 + wave * 16 + l16;
        bf16* orow = Ob + (size_t)(b * cS + token) * (cNH * cHD) + h * cHD;
        #pragma unroll
        for (int dt = 0; dt < 8; ++dt) {
            bf16x4 o4;
            #pragma unroll
            for (int r = 0; r < 4; ++r) o4[r] = (bf16)(oac[dt][r] * inv);
            *(bf16x4*)&orow[dt * 16 + quad * 4] = o4;
        }
    }
}

extern "C" void kernel_launch(void* const* d_in, const int* in_sizes, int n_in,
                              void* d_out, int out_size, void* d_ws, size_t ws_size,
                              hipStream_t stream) {
    const float* x    = (const float*)d_in[0];
    const float* cosb = (const float*)d_in[1];
    const float* sinb = (const float*)d_in[2];
    // d_in[3] = attention_mask (exactly causal NEG) — implemented analytically
    const float* qw = (const float*)d_in[4];
    const float* kw = (const float*)d_in[5];
    const float* vw = (const float*)d_in[6];
    const float* qb = (const float*)d_in[7];
    const float* kb_ = (const float*)d_in[8];
    const float* vb = (const float*)d_in[9];
    const float* qA = (const float*)d_in[10];
    const float* qB = (const float*)d_in[11];
    const float* kA = (const float*)d_in[12];
    const float* kB = (const float*)d_in[13];
    const float* vA = (const float*)d_in[14];
    const float* vB = (const float*)d_in[15];
    const float* ow = (const float*)d_in[16];
    float* out = (float*)d_out;

    char* ws = (char*)d_ws;
    bf16* Xbf   = (bf16*)ws;  ws += (size_t)cNTOK * cH * 2;            // 16.8 MB
    bf16* Wc    = (bf16*)ws;  ws += (size_t)cNQKV * cH * 2;            // 12.6 MB
    float* biasc = (float*)ws; ws += (size_t)cNQKV * 4;                // 12 KB
    bf16* Qr    = (bf16*)ws;  ws += (size_t)cB * cNH * cS * cHD * 2;   // 16.8 MB
    bf16* Kr    = (bf16*)ws;  ws += (size_t)cB * cKVH * cS * cHD * 2;  // 4.2 MB
    bf16* Vt    = (bf16*)ws;  ws += (size_t)cB * cKVH * cHD * cS * 2;  // 4.2 MB
    bf16* OWbf  = (bf16*)ws;  ws += (size_t)cH * cH * 2;               // 8.4 MB
    bf16* Aout  = (bf16*)ws;  ws += (size_t)cNTOK * cQD * 2;           // 16.8 MB

    conv_f32_bf16<<<(cNTOK * cH) / 1024, 256, 0, stream>>>(x, Xbf);
    conv_f32_bf16<<<(cH * cH) / 1024, 256, 0, stream>>>(ow, OWbf);
    prep_w<<<(cNQKV * cH) / 256, 256, 0, stream>>>(qw, kw, vw, qA, qB, kA, kB, vA, vB, Wc);
    prep_bias<<<(cNQKV + 255) / 256, 256, 0, stream>>>(qb, kb_, vb, biasc);

    // QKV projection with fused bias+RoPE+reorder+V-transpose
    gemm_qkv<<<dim3(cNQKV / 128, cNTOK / 128), 256, 0, stream>>>(Xbf, Wc, biasc, cosb, sinb, Qr, Kr, Vt);

    flash4<<<dim3(16, cNH, cB), 256, 0, stream>>>(Qr, Kr, Vt, Aout);

    gemm_bt_f32<<<dim3(cH / 128, cNTOK / 128), 256, 0, stream>>>(Aout, OWbf, out, cNTOK, cH, cH);
}